// Round 12
// baseline (1990.807 us; speedup 1.0000x reference)
//
#include <hip/hip_runtime.h>

// f32-rounded scalars (jax weak-scalar semantics)
#define ALPHA_F ((float)0.8187307530779818)
#define BETA_F  ((float)0.9048374180359595)

// V4 = V3 with (a) PLAIN stores (V3's nontemporal stores caused 14x write and
// 57x fetch amplification vs V2's ideal-traffic plain stores), (b) XCD-aware
// h-chunk swizzle so h-adjacent blocks (sharing conv rows) land on one XCD L2.
// All arithmetic chains identical to the bit-exact V2/V3 (absmax 0.0).
__global__ __launch_bounds__(512) void snn_v4(
    const float* __restrict__ x, const float* __restrict__ wq,
    const float* __restrict__ bvec, float* __restrict__ out)
{
    __shared__ float wl[32][54];            // raw weights [o][ci*27+kt*9+kh*3+kw]
    __shared__ float wp[32][54];            // permuted    [o][((kt*3+kh)*3+kw)*2+ci]
    __shared__ __align__(16) float Dl[32][32];  // gram [cp][c]
    __shared__ float invl[32];
    __shared__ float biasl[32];
    __shared__ unsigned char msk[2][64][8]; // [parity][w][wave] spike nibbles

    const int tid = threadIdx.x;
    const int w  = tid & 63;
    const int wv = tid >> 6;        // 0..7
    const int c0 = wv * 4;          // my 4 channels
    // XCD swizzle: consecutive blockIdx round-robin across 8 XCDs; give each
    // XCD a contiguous h-chunk: h = (idx&7)*8 + ((idx>>3)&7)  (bijective).
    const int idx = blockIdx.x;
    const int b = idx >> 6;
    const int h = ((idx & 7) << 3) | ((idx >> 3) & 7);

    // ---- stage weights ----
    for (int i = tid; i < 1728; i += 512) wl[i / 54][i % 54] = wq[i];
    __syncthreads();
    // permuted copy (Eigen conv tap order) + gram (sequential FMA chain, k asc)
    for (int i = tid; i < 1728; i += 512) {
        int c = i / 54, j = i % 54;
        int ci = j & 1, r = j >> 1;
        int kw_ = r % 3, kh_ = (r / 3) % 3, kt_ = r / 9;
        wp[c][j] = wl[c][ci * 27 + kt_ * 9 + kh_ * 3 + kw_];
    }
    for (int e = tid; e < 1024; e += 512) {
        int cp = e >> 5, c = e & 31;
        float s = 0.f;
        #pragma unroll
        for (int k = 0; k < 54; ++k) s = fmaf(wl[cp][k], wl[c][k], s);
        Dl[cp][c] = s;
    }
    __syncthreads();
    if (tid < 32) {
        float s = 0.f;
        #pragma unroll
        for (int k = 0; k < 54; ++k)
            s = __fadd_rn(s, __fmul_rn(wl[tid][k], wl[tid][k]));
        invl[tid] = 1.0f / __fadd_rn(s, 1e-8f);
        biasl[tid] = bvec[tid];
    }
    __syncthreads();

    float mem[4], syn[4];
    #pragma unroll
    for (int cl = 0; cl < 4; ++cl) { mem[cl] = 0.f; syn[cl] = 0.f; }
    unsigned mask = 0u;

    float inv_r[4], bias_r[4];
    #pragma unroll
    for (int cl = 0; cl < 4; ++cl) { inv_r[cl] = invl[c0 + cl]; bias_r[cl] = biasl[c0 + cl]; }

    const size_t xb = (size_t)b * 524288;
    const size_t ob = (size_t)b * 8388608 + (size_t)c0 * 262144 + (size_t)h * 64 + (size_t)w;

    for (int t = 0; t < 64; ++t) {
        // ---- rst: fmaf(s, D, rst), s in {0,1}, cp ascending (bit-equal to ref) ----
        float rst[4] = {0.f, 0.f, 0.f, 0.f};
        if (__ballot(mask != 0u)) {
            #pragma unroll
            for (int cp = 0; cp < 32; ++cp) {
                float s = ((mask >> cp) & 1u) ? 1.0f : 0.0f;
                const float4 dv = *(const float4*)&Dl[cp][c0];
                rst[0] = fmaf(s, dv.x, rst[0]);
                rst[1] = fmaf(s, dv.y, rst[1]);
                rst[2] = fmaf(s, dv.z, rst[2]);
                rst[3] = fmaf(s, dv.w, rst[3]);
            }
        }

        // ---- mem update (OLD syn), spike, store (PLAIN stores), nibble ----
        unsigned nib = 0u;
        #pragma unroll
        for (int cl = 0; cl < 4; ++cl) {
            float bm = __fmul_rn(BETA_F, mem[cl]);
            float bs = __fadd_rn(bm, syn[cl]);
            mem[cl] = __fsub_rn(bs, rst[cl]);
            float mthr = __fsub_rn(__fmul_rn(mem[cl], inv_r[cl]), bias_r[cl]);
            bool s = mthr > 0.f;
            nib |= (s ? 1u : 0u) << cl;
            out[ob + (size_t)cl * 262144 + (size_t)t * 4096] = s ? 1.0f : 0.0f;
        }
        msk[t & 1][w][wv] = (unsigned char)nib;

        // ---- conv: per-channel single FMA chain, (kt,kh,kw,ci) order (== V2) ----
        float acc[4] = {0.f, 0.f, 0.f, 0.f};
        #pragma unroll
        for (int kt = 0; kt < 3; ++kt) {
            int tt = t + kt - 1;
            bool tok = (unsigned)tt < 64u;
            int ttc = tok ? tt : 0;
            #pragma unroll
            for (int kh = 0; kh < 3; ++kh) {
                int hh = h + kh - 1;
                bool hok = (unsigned)hh < 64u;
                int hhc = hok ? hh : 0;
                bool rowok = tok && hok;
                const float* rp0 = x + xb + (size_t)(ttc * 4096 + hhc * 64);
                const float* rp1 = rp0 + 262144;
                float x00 = (rowok && w > 0)  ? rp0[w - 1] : 0.f;
                float x01 = (rowok && w > 0)  ? rp1[w - 1] : 0.f;
                float x10 = rowok             ? rp0[w]     : 0.f;
                float x11 = rowok             ? rp1[w]     : 0.f;
                float x20 = (rowok && w < 63) ? rp0[w + 1] : 0.f;
                float x21 = (rowok && w < 63) ? rp1[w + 1] : 0.f;
                const int j0 = (kt * 3 + kh) * 6;
                #pragma unroll
                for (int cl = 0; cl < 4; ++cl) {
                    float a = acc[cl];
                    a = fmaf(x00, wp[c0 + cl][j0 + 0], a);
                    a = fmaf(x01, wp[c0 + cl][j0 + 1], a);
                    a = fmaf(x10, wp[c0 + cl][j0 + 2], a);
                    a = fmaf(x11, wp[c0 + cl][j0 + 3], a);
                    a = fmaf(x20, wp[c0 + cl][j0 + 4], a);
                    a = fmaf(x21, wp[c0 + cl][j0 + 5], a);
                    acc[cl] = a;
                }
            }
        }
        #pragma unroll
        for (int cl = 0; cl < 4; ++cl)
            syn[cl] = __fadd_rn(__fmul_rn(ALPHA_F, syn[cl]), acc[cl]);

        // ---- one barrier per t (parity-double-buffered nibble exchange) ----
        __syncthreads();
        const uint2 mv = *(const uint2*)&msk[t & 1][w][0];
        unsigned lo = (mv.x | (mv.x >> 4)) & 0x00FF00FFu;
        lo = (lo | (lo >> 8)) & 0xFFFFu;
        unsigned hi = (mv.y | (mv.y >> 4)) & 0x00FF00FFu;
        hi = (hi | (hi >> 8)) & 0xFFFFu;
        mask = lo | (hi << 16);
    }
}

extern "C" void kernel_launch(void* const* d_in, const int* in_sizes, int n_in,
                              void* d_out, int out_size, void* d_ws, size_t ws_size,
                              hipStream_t stream) {
    const float* x  = (const float*)d_in[0];
    const float* wq = (const float*)d_in[1];
    const float* bv = (const float*)d_in[2];
    for (int i = 0; i < n_in; ++i) {
        int sz = in_sizes[i];
        if (sz == 8 * 2 * 64 * 64 * 64) x  = (const float*)d_in[i];
        else if (sz == 32 * 2 * 27)     wq = (const float*)d_in[i];
        else if (sz == 32)              bv = (const float*)d_in[i];
    }
    float* out = (float*)d_out;
    snn_v4<<<512, 512, 0, stream>>>(x, wq, bv, out);
}

// Round 13
// 1882.986 us; speedup vs baseline: 1.0573x; 1.0573x over previous
//
#include <hip/hip_runtime.h>

// f32-rounded scalars (jax weak-scalar semantics)
#define ALPHA_F ((float)0.8187307530779818)
#define BETA_F  ((float)0.9048374180359595)

// V5 = V4 with the store path rebuilt: spikes staged in LDS (parity dbuf),
// flushed after the per-t barrier as ONE float4 store per thread (each 128B
// line delivered by a single quarter-wave request). V3/V4 showed 14x write /
// 60x fetch HBM amplification with per-lane-dword stores under high wave
// concurrency; V2 (low concurrency, same instruction shape) had perfect
// traffic. Arithmetic chains bit-identical to V2/V3/V4 (absmax 0.0).
__global__ __launch_bounds__(512) void snn_v5(
    const float* __restrict__ x, const float* __restrict__ wq,
    const float* __restrict__ bvec, float* __restrict__ out)
{
    __shared__ float wl[32][54];            // raw weights [o][ci*27+kt*9+kh*3+kw]
    __shared__ float wp[32][54];            // permuted    [o][((kt*3+kh)*3+kw)*2+ci]
    __shared__ __align__(16) float Dl[32][32];  // gram [cp][c]
    __shared__ float invl[32];
    __shared__ float biasl[32];
    __shared__ unsigned char msk[2][64][8];     // [parity][w][wave] spike nibbles
    __shared__ __align__(16) float sbuf[2][32][64]; // [parity][c][w] spike planes

    const int tid = threadIdx.x;
    const int w  = tid & 63;
    const int wv = tid >> 6;        // 0..7
    const int c0 = wv * 4;          // my 4 channels
    const int idx = blockIdx.x;
    const int b = idx >> 6;
    const int h = ((idx & 7) << 3) | ((idx >> 3) & 7);  // XCD h-chunk swizzle

    // ---- stage weights ----
    for (int i = tid; i < 1728; i += 512) wl[i / 54][i % 54] = wq[i];
    __syncthreads();
    for (int i = tid; i < 1728; i += 512) {
        int c = i / 54, j = i % 54;
        int ci = j & 1, r = j >> 1;
        int kw_ = r % 3, kh_ = (r / 3) % 3, kt_ = r / 9;
        wp[c][j] = wl[c][ci * 27 + kt_ * 9 + kh_ * 3 + kw_];
    }
    for (int e = tid; e < 1024; e += 512) {
        int cp = e >> 5, c = e & 31;
        float s = 0.f;
        #pragma unroll
        for (int k = 0; k < 54; ++k) s = fmaf(wl[cp][k], wl[c][k], s);
        Dl[cp][c] = s;
    }
    __syncthreads();
    if (tid < 32) {
        float s = 0.f;
        #pragma unroll
        for (int k = 0; k < 54; ++k)
            s = __fadd_rn(s, __fmul_rn(wl[tid][k], wl[tid][k]));
        invl[tid] = 1.0f / __fadd_rn(s, 1e-8f);
        biasl[tid] = bvec[tid];
    }
    __syncthreads();

    float mem[4], syn[4];
    #pragma unroll
    for (int cl = 0; cl < 4; ++cl) { mem[cl] = 0.f; syn[cl] = 0.f; }
    unsigned mask = 0u;

    float inv_r[4], bias_r[4];
    #pragma unroll
    for (int cl = 0; cl < 4; ++cl) { inv_r[cl] = invl[c0 + cl]; bias_r[cl] = biasl[c0 + cl]; }

    const size_t xb = (size_t)b * 524288;
    // flush mapping: thread stores c=tid>>4, 4 w's starting at (tid&15)*4
    const int fc = tid >> 4, fl = tid & 15;
    float* fout = out + (size_t)b * 8388608 + (size_t)fc * 262144
                + (size_t)h * 64 + (size_t)(fl * 4);

    for (int t = 0; t < 64; ++t) {
        // ---- rst: fmaf(s, D, rst), s in {0,1}, cp ascending (bit-equal) ----
        float rst[4] = {0.f, 0.f, 0.f, 0.f};
        if (__ballot(mask != 0u)) {
            #pragma unroll
            for (int cp = 0; cp < 32; ++cp) {
                float s = ((mask >> cp) & 1u) ? 1.0f : 0.0f;
                const float4 dv = *(const float4*)&Dl[cp][c0];
                rst[0] = fmaf(s, dv.x, rst[0]);
                rst[1] = fmaf(s, dv.y, rst[1]);
                rst[2] = fmaf(s, dv.z, rst[2]);
                rst[3] = fmaf(s, dv.w, rst[3]);
            }
        }

        // ---- mem update (OLD syn), spike -> LDS plane + nibble ----
        const int par = t & 1;
        unsigned nib = 0u;
        #pragma unroll
        for (int cl = 0; cl < 4; ++cl) {
            float bm = __fmul_rn(BETA_F, mem[cl]);
            float bs = __fadd_rn(bm, syn[cl]);
            mem[cl] = __fsub_rn(bs, rst[cl]);
            float mthr = __fsub_rn(__fmul_rn(mem[cl], inv_r[cl]), bias_r[cl]);
            bool s = mthr > 0.f;
            nib |= (s ? 1u : 0u) << cl;
            sbuf[par][c0 + cl][w] = s ? 1.0f : 0.0f;
        }
        msk[par][w][wv] = (unsigned char)nib;

        __syncthreads();   // sbuf + msk complete (parity dbuf makes reuse safe)

        // ---- flush: ONE float4 store per thread (line-atomic assembly) ----
        const float4 sv = *(const float4*)&sbuf[par][fc][fl * 4];
        *(float4*)(fout + (size_t)t * 4096) = sv;

        // ---- assemble 32-bit spike mask from nibbles ----
        const uint2 mv = *(const uint2*)&msk[par][w][0];
        unsigned lo = (mv.x | (mv.x >> 4)) & 0x00FF00FFu;
        lo = (lo | (lo >> 8)) & 0xFFFFu;
        unsigned hi = (mv.y | (mv.y >> 4)) & 0x00FF00FFu;
        hi = (hi | (hi >> 8)) & 0xFFFFu;
        mask = lo | (hi << 16);

        // ---- conv: per-channel single FMA chain, (kt,kh,kw,ci) order (== V2) ----
        float acc[4] = {0.f, 0.f, 0.f, 0.f};
        #pragma unroll
        for (int kt = 0; kt < 3; ++kt) {
            int tt = t + kt - 1;
            bool tok = (unsigned)tt < 64u;
            int ttc = tok ? tt : 0;
            #pragma unroll
            for (int kh = 0; kh < 3; ++kh) {
                int hh = h + kh - 1;
                bool hok = (unsigned)hh < 64u;
                int hhc = hok ? hh : 0;
                bool rowok = tok && hok;
                const float* rp0 = x + xb + (size_t)(ttc * 4096 + hhc * 64);
                const float* rp1 = rp0 + 262144;
                float x00 = (rowok && w > 0)  ? rp0[w - 1] : 0.f;
                float x01 = (rowok && w > 0)  ? rp1[w - 1] : 0.f;
                float x10 = rowok             ? rp0[w]     : 0.f;
                float x11 = rowok             ? rp1[w]     : 0.f;
                float x20 = (rowok && w < 63) ? rp0[w + 1] : 0.f;
                float x21 = (rowok && w < 63) ? rp1[w + 1] : 0.f;
                const int j0 = (kt * 3 + kh) * 6;
                #pragma unroll
                for (int cl = 0; cl < 4; ++cl) {
                    float a = acc[cl];
                    a = fmaf(x00, wp[c0 + cl][j0 + 0], a);
                    a = fmaf(x01, wp[c0 + cl][j0 + 1], a);
                    a = fmaf(x10, wp[c0 + cl][j0 + 2], a);
                    a = fmaf(x11, wp[c0 + cl][j0 + 3], a);
                    a = fmaf(x20, wp[c0 + cl][j0 + 4], a);
                    a = fmaf(x21, wp[c0 + cl][j0 + 5], a);
                    acc[cl] = a;
                }
            }
        }
        #pragma unroll
        for (int cl = 0; cl < 4; ++cl)
            syn[cl] = __fadd_rn(__fmul_rn(ALPHA_F, syn[cl]), acc[cl]);
    }
}

extern "C" void kernel_launch(void* const* d_in, const int* in_sizes, int n_in,
                              void* d_out, int out_size, void* d_ws, size_t ws_size,
                              hipStream_t stream) {
    const float* x  = (const float*)d_in[0];
    const float* wq = (const float*)d_in[1];
    const float* bv = (const float*)d_in[2];
    for (int i = 0; i < n_in; ++i) {
        int sz = in_sizes[i];
        if (sz == 8 * 2 * 64 * 64 * 64) x  = (const float*)d_in[i];
        else if (sz == 32 * 2 * 27)     wq = (const float*)d_in[i];
        else if (sz == 32)              bv = (const float*)d_in[i];
    }
    float* out = (float*)d_out;
    snn_v5<<<512, 512, 0, stream>>>(x, wq, bv, out);
}